// Round 17
// baseline (448.727 us; speedup 1.0000x reference)
//
#include <hip/hip_runtime.h>

typedef unsigned short u16;
typedef __attribute__((ext_vector_type(8))) short bf16x8;
typedef __attribute__((ext_vector_type(4))) float f32x4;

#define NB 4
#define NT 1024
#define NC 768
#define NH 12
#define HD 64
#define NBLK 768

__device__ __forceinline__ u16 f2bf(float f) {
  union { float f; unsigned u; } v; v.f = f;
  unsigned r = v.u + 0x7FFFu + ((v.u >> 16) & 1u);
  return (u16)(r >> 16);
}
__device__ __forceinline__ float bf2f(u16 h) {
  union { unsigned u; float f; } v; v.u = ((unsigned)h) << 16;
  return v.f;
}

__device__ __forceinline__ void gld16(const u16* g, u16* l) {
  __builtin_amdgcn_global_load_lds((const __attribute__((address_space(1))) void*)g,
                                   (__attribute__((address_space(3))) void*)l, 16, 0, 0);
}

// Device-scope grid barrier: all NBLK blocks co-resident by construction
// (LDS 42KB -> 3 blocks/CU x 256 CU = 768; launch_bounds(256,3) caps VGPR).
// Release: syncthreads drains block's mem ops; threadfence publishes device-wide
// (cross-XCD L2). Acquire: threadfence invalidates stale cache after the count.
__device__ __forceinline__ void gridbar(unsigned* c) {
  __syncthreads();
  if (threadIdx.x == 0) {
    __threadfence();
    __hip_atomic_fetch_add(c, 1u, __ATOMIC_ACQ_REL, __HIP_MEMORY_SCOPE_AGENT);
    while (__hip_atomic_load(c, __ATOMIC_ACQUIRE, __HIP_MEMORY_SCOPE_AGENT) < (unsigned)NBLK)
      __builtin_amdgcn_s_sleep(8);
    __threadfence();
  }
  __syncthreads();
}

__global__ __launch_bounds__(256, 3) void mega_k(
    const float* __restrict__ x, const float* __restrict__ Wq, const float* __restrict__ Wk,
    const float* __restrict__ Wv, const float* __restrict__ Wp, const float* __restrict__ w1,
    const float* __restrict__ b1, const float* __restrict__ w2, const float* __restrict__ b2,
    const float* __restrict__ cP, const float* __restrict__ LmP,
    u16* __restrict__ xb, u16* __restrict__ Wt, u16* __restrict__ Wtp,
    u16* __restrict__ Qp, u16* __restrict__ Kp, u16* __restrict__ Vp,
    u16* __restrict__ ebias, u16* __restrict__ Yb, float* __restrict__ out,
    unsigned* __restrict__ bar) {
  __shared__ __align__(16) u16 smem[20992];  // 41984 B = max(attn 41984, qkv 18944, prep 8320)
  const int bid = blockIdx.x;
  const int tid = threadIdx.x;

  // ================= phase 0: conv_x (vb<1536) | conv_w (vb>=1536) =================
  for (int vb = bid; vb < 2112; vb += NBLK) {
    if (vb < 1536) {
      const int base = vb * 2048 + tid * 8;
      const f32x4* xv = (const f32x4*)(x + base);
      f32x4 v0 = xv[0], v1 = xv[1];
      bf16x8 o;
#pragma unroll
      for (int j = 0; j < 4; ++j) {
        o[j] = (short)f2bf(v0[j]);
        o[4 + j] = (short)f2bf(v1[j]);
      }
      *(bf16x8*)(xb + base) = o;
    } else {
      u16(*tile)[65] = (u16(*)[65])smem;
      int idx = vb - 1536;
      int z = idx / 144, rem = idx - z * 144;
      int k0 = (rem / 12) * 64, n0 = (rem % 12) * 64;
      const float* src = (z == 0) ? Wq : (z == 1) ? Wk : (z == 2) ? Wv : Wp;
      const int c = tid & 63, r4 = tid >> 6;
#pragma unroll
      for (int p = 0; p < 16; ++p) {
        int kk = p * 4 + r4;
        tile[kk][c] = f2bf(src[(size_t)(k0 + kk) * NC + n0 + c]);
      }
      __syncthreads();
      u16* dst = (z < 3) ? (Wt + (size_t)z * NC * NC) : Wtp;
#pragma unroll
      for (int p = 0; p < 16; ++p) {
        int nn = p * 4 + r4;
        dst[(size_t)(n0 + nn) * NC + k0 + c] = tile[c][nn];
      }
      __syncthreads();  // protect tile for potential next iteration
    }
  }
  gridbar(bar + 0);

  // ================= phase 1: QKV GEMM+RoPE (bid<576) | fire table (bid>=576) =================
  if (bid >= 576) {
    float c = cP[0], Lm = LmP[0];
    float thresh = fabsf(Lm * 512.0f);
    for (int q = bid - 576; q < 1024; q += 192) {
      float pn = fmaxf((float)q, thresh);
      float inv_nl = 1.0f / (logf(fabsf(c * pn) + 1.0f) + 1e-6f);
      for (int idx = tid; idx < 384; idx += 256) {
        int rel = idx - 64;
        float outv[NH];
        if (rel >= 0 && rel <= 256) {
          float z = logf(fabsf(c * (float)rel) + 1.0f) * inv_nl;
          float acc[NH];
#pragma unroll
          for (int hh = 0; hh < NH; ++hh) acc[hh] = b2[hh];
#pragma unroll
          for (int j = 0; j < 32; ++j) {
            float hj = fmaxf(z * w1[j] + b1[j], 0.0f);
#pragma unroll
            for (int hh = 0; hh < NH; ++hh) acc[hh] += hj * w2[j * NH + hh];
          }
#pragma unroll
          for (int hh = 0; hh < NH; ++hh) outv[hh] = __expf(acc[hh]);
        } else {
#pragma unroll
          for (int hh = 0; hh < NH; ++hh) outv[hh] = 0.0f;
        }
#pragma unroll
        for (int hh = 0; hh < NH; ++hh)
          ebias[((size_t)hh * NT + q) * 384 + idx] = f2bf(outv[hh]);
      }
    }
  } else {
    constexpr int K = NC;
    u16* As = smem;
    u16* Bs = smem + 4096;
    const int lin = (bid & 7) * 72 + (bid >> 3);  // XCD swizzle (576 = 8*72 exact)
    const int m0 = (lin & 31) * 128, n0 = (lin >> 5) * 128;
    const int wid = tid >> 6, lane = tid & 63;
    const int wr = wid >> 1, wc = wid & 1;
    const int lr = lane & 15, lg = lane >> 4, lk = lg << 3;
    const int srow = wid * 16 + (lane >> 2);
    const int scol = (lane & 3) * 8;
    f32x4 acc[4][4] = {};
    const u16* Ag = xb + (size_t)(m0 + srow) * K + scol;
    const u16* Bg = Wt + (size_t)(n0 + srow) * K + scol;
    u16* Al = &As[(wid * 16) * 32];
    u16* Bl = &Bs[(wid * 16) * 32];

    for (int k0 = 0; k0 < K; k0 += 32) {
      gld16(Ag + k0, Al);
      gld16(Ag + (size_t)64 * K + k0, Al + 64 * 32);
      gld16(Bg + k0, Bl);
      gld16(Bg + (size_t)64 * K + k0, Bl + 64 * 32);
      __syncthreads();
      bf16x8 af[4], bfv[4];
#pragma unroll
      for (int i = 0; i < 4; ++i)
        af[i] = *(const bf16x8*)&As[(wr * 64 + i * 16 + lr) * 32 + lk];
#pragma unroll
      for (int j = 0; j < 4; ++j)
        bfv[j] = *(const bf16x8*)&Bs[(wc * 64 + j * 16 + lr) * 32 + lk];
#pragma unroll
      for (int i = 0; i < 4; ++i)
#pragma unroll
        for (int j = 0; j < 4; ++j)
          acc[i][j] = __builtin_amdgcn_mfma_f32_16x16x32_bf16(af[i], bfv[j], acc[i][j], 0, 0, 0);
      __syncthreads();  // also fences smem for epilogue reuse (vtx)
    }

    const int rbase = lg * 4;
    const int base_col = n0 + wc * 64;
    const int part = base_col / 768;         // 0=Q 1=K 2=V
    const int h = (base_col % 768) >> 6;
    const int b = m0 >> 10;
    const int bh = b * NH + h;
    const int tbase = (m0 & 1023) + wr * 64;

    if (part < 2) {
      u16* dst = (part == 0 ? Qp : Kp) + ((size_t)bh << 16);
      const float inv0 = __expf(-(float)lr * 0.28782313662425f);          // 10000^(-lr/32)
      const float inv1 = __expf(-(float)(lr + 16) * 0.28782313662425f);
#pragma unroll
      for (int i = 0; i < 4; ++i)
#pragma unroll
        for (int rr = 0; rr < 4; ++rr) {
          const int tl = tbase + i * 16 + rbase + rr;
          float s0, c0, s1, c1;
          __sincosf((float)tl * inv0, &s0, &c0);
          __sincosf((float)tl * inv1, &s1, &c1);
          const float a0 = acc[i][0][rr], a1 = acc[i][1][rr];
          const float a2 = acc[i][2][rr], a3 = acc[i][3][rr];
          const size_t ro = (size_t)tl * HD;
          dst[ro + lr]      = f2bf(a0 * c0 - a2 * s0);
          dst[ro + 16 + lr] = f2bf(a1 * c1 - a3 * s1);
          dst[ro + 32 + lr] = f2bf(a0 * s0 + a2 * c0);
          dst[ro + 48 + lr] = f2bf(a1 * s1 + a3 * c1);
        }
    } else {
      u16* dst = Vp + ((size_t)bh << 16);
      u16* vb = smem + wid * 64 * 37;        // per-wave [64][37] transpose buffer
#pragma unroll
      for (int hf = 0; hf < 2; ++hf) {
#pragma unroll
        for (int i = 0; i < 4; ++i)
#pragma unroll
          for (int rr = 0; rr < 4; ++rr) {
            const int row = i * 16 + rbase + rr;
            vb[row * 37 + lr]      = f2bf(acc[i][2 * hf][rr]);
            vb[row * 37 + 16 + lr] = f2bf(acc[i][2 * hf + 1][rr]);
          }
        asm volatile("s_waitcnt lgkmcnt(0)" ::: "memory");
#pragma unroll
        for (int p = 0; p < 32; ++p) {
          const int d = hf * 32 + p;
          dst[(size_t)d * NT + tbase + lane] = vb[lane * 37 + p];
        }
      }
    }
  }
  gridbar(bar + 1);

  // ================= phase 2: windowed attention (1:1, 768 blocks) =================
  {
    u16* KsB = smem;                 // [2][64][64]
    u16* VsB = smem + 8192;          // [2][64][64]
    const int xcd = bid & 7, jj = bid >> 3;
    const int qb = jj & 15, t6 = jj >> 4;
    const int yslot = xcd * 6 + t6;
    const int b = yslot & 3, h = yslot >> 2;
    const int bh = b * NH + h;
    const int Q0 = qb << 6;
    const int wid = tid >> 6, lane = tid & 63;
    const int q0 = Q0 + wid * 16;
    const int lr = lane & 15, lg = lane >> 4, lk = lg << 3;
    const u16* Qb = Qp + ((size_t)bh << 16);
    const u16* Kb = Kp + ((size_t)bh << 16);
    const u16* Vb = Vp + ((size_t)bh << 16);
    const u16* ebh = ebias + (size_t)h * NT * 384;
    u16(*pl)[72] = (u16(*)[72])(smem + 16384 + wid * 1152);  // [16][72] per wave

    bf16x8 aq0 = *(const bf16x8*)(Qb + (q0 + lr) * HD + lk);
    bf16x8 aq1 = *(const bf16x8*)(Qb + (q0 + lr) * HD + 32 + lk);
    bf16x8 ones;
#pragma unroll
    for (int i = 0; i < 8; ++i) ones[i] = (short)0x3F80;  // bf16 1.0
    f32x4 yacc[4] = {};
    f32x4 lsum = {};

    int cstart = Q0 - 256;
    if (cstart < 0) cstart = 0;
    const int n = ((Q0 + 64) - cstart) >> 6;

    const int srow = lane >> 3;
    const int sseg = (lane & 7) ^ srow;
    auto STAGE = [&](int buf, int c) {
#pragma unroll
      for (int i = 0; i < 2; ++i) {
        const int rb = (i * 4 + wid) * 8;
        gld16(Kb + (size_t)(c + rb + srow) * HD + sseg * 8, KsB + buf * 4096 + rb * 64);
        gld16(Vb + (size_t)(rb + srow) * NT + c + sseg * 8, VsB + buf * 4096 + rb * 64);
      }
    };
    auto LOADEB = [&](float (&e)[4][4], int c) {
#pragma unroll
      for (int kk = 0; kk < 4; ++kk) {
        const int kcol = c + kk * 16 + lr;
#pragma unroll
        for (int r = 0; r < 4; ++r) {
          int qrow = q0 + lg * 4 + r;
          int idx = qrow - kcol + 64;
          idx = idx < 0 ? 0 : (idx > 383 ? 383 : idx);
          e[kk][r] = bf2f(ebh[(size_t)qrow * 384 + idx]);
        }
      }
    };

    STAGE(0, cstart);
    float ebc[4][4];
    LOADEB(ebc, cstart);
    __syncthreads();

    int c = cstart;
    for (int ci = 0; ci < n; ++ci, c += 64) {
      const int cur = ci & 1;
      const bool more = (ci + 1 < n);
      if (more) STAGE(cur ^ 1, c + 64);
      float ebn[4][4];
      if (more) LOADEB(ebn, c + 64);
      const int rsw = (lr & 7) << 4;
#pragma unroll
      for (int kk = 0; kk < 4; ++kk) {
        const char* krow = (const char*)(KsB + cur * 4096 + (kk * 16 + lr) * 64);
        bf16x8 bk0 = *(const bf16x8*)(krow + ((lg * 16) ^ rsw));
        bf16x8 bk1 = *(const bf16x8*)(krow + ((lg * 16 + 64) ^ rsw));
        f32x4 t = {};
        t = __builtin_amdgcn_mfma_f32_16x16x32_bf16(aq0, bk0, t, 0, 0, 0);
        t = __builtin_amdgcn_mfma_f32_16x16x32_bf16(aq1, bk1, t, 0, 0, 0);
#pragma unroll
        for (int r = 0; r < 4; ++r) {
          float p = __expf(t[r] * 0.125f) * ebc[kk][r];
          pl[lg * 4 + r][kk * 16 + lr] = f2bf(p);
        }
      }
      asm volatile("s_waitcnt lgkmcnt(0)" ::: "memory");
      bf16x8 ap0 = *(const bf16x8*)&pl[lr][lk];
      bf16x8 ap1 = *(const bf16x8*)&pl[lr][32 + lk];
      lsum = __builtin_amdgcn_mfma_f32_16x16x32_bf16(ap0, ones, lsum, 0, 0, 0);
      lsum = __builtin_amdgcn_mfma_f32_16x16x32_bf16(ap1, ones, lsum, 0, 0, 0);
#pragma unroll
      for (int dt = 0; dt < 4; ++dt) {
        const char* vrow = (const char*)(VsB + cur * 4096 + (dt * 16 + lr) * 64);
        bf16x8 bv0 = *(const bf16x8*)(vrow + ((lg * 16) ^ rsw));
        bf16x8 bv1 = *(const bf16x8*)(vrow + ((lg * 16 + 64) ^ rsw));
        yacc[dt] = __builtin_amdgcn_mfma_f32_16x16x32_bf16(ap0, bv0, yacc[dt], 0, 0, 0);
        yacc[dt] = __builtin_amdgcn_mfma_f32_16x16x32_bf16(ap1, bv1, yacc[dt], 0, 0, 0);
      }
      if (more) {
#pragma unroll
        for (int kk = 0; kk < 4; ++kk)
#pragma unroll
          for (int r = 0; r < 4; ++r) ebc[kk][r] = ebn[kk][r];
      }
      __syncthreads();
    }

    float linv[4];
#pragma unroll
    for (int r = 0; r < 4; ++r) linv[r] = 1.0f / lsum[r];
#pragma unroll
    for (int dt = 0; dt < 4; ++dt)
#pragma unroll
      for (int r = 0; r < 4; ++r) {
        int qrow = q0 + lg * 4 + r;
        int d = dt * 16 + lr;
        Yb[(size_t)(b * NT + qrow) * NC + h * HD + d] = f2bf(yacc[dt][r] * linv[r]);
      }
  }
  gridbar(bar + 2);

  // ================= phase 3: proj GEMM, 64x64 tiles (768 = 64x12 exact) =================
  {
    u16* As = smem;          // 2048 el
    u16* Bs = smem + 2048;   // 2048 el
    const int m0 = (bid & 63) * 64, n0 = (bid >> 6) * 64;
    const int wid = tid >> 6, lane = tid & 63;
    const int wr = wid >> 1, wc = wid & 1;
    const int lr = lane & 15, lk = (lane >> 4) << 3;
    const int srow = wid * 16 + (lane >> 2);
    const int scol = (lane & 3) * 8;
    f32x4 acc[2][2] = {};
    const u16* Ag = Yb + (size_t)(m0 + srow) * NC + scol;
    const u16* Bg = Wtp + (size_t)(n0 + srow) * NC + scol;
    u16* Al = &As[(wid * 16) * 32];
    u16* Bl = &Bs[(wid * 16) * 32];

    for (int k0 = 0; k0 < NC; k0 += 32) {
      gld16(Ag + k0, Al);
      gld16(Bg + k0, Bl);
      __syncthreads();
      bf16x8 af[2], bfv[2];
#pragma unroll
      for (int i = 0; i < 2; ++i)
        af[i] = *(const bf16x8*)&As[(wr * 32 + i * 16 + lr) * 32 + lk];
#pragma unroll
      for (int j = 0; j < 2; ++j)
        bfv[j] = *(const bf16x8*)&Bs[(wc * 32 + j * 16 + lr) * 32 + lk];
#pragma unroll
      for (int i = 0; i < 2; ++i)
#pragma unroll
        for (int j = 0; j < 2; ++j)
          acc[i][j] = __builtin_amdgcn_mfma_f32_16x16x32_bf16(af[i], bfv[j], acc[i][j], 0, 0, 0);
      __syncthreads();
    }
    const int rbase = (lane >> 4) * 4;
#pragma unroll
    for (int i = 0; i < 2; ++i)
#pragma unroll
      for (int j = 0; j < 2; ++j)
#pragma unroll
        for (int r = 0; r < 4; ++r) {
          size_t row = m0 + wr * 32 + i * 16 + rbase + r;
          size_t col = n0 + wc * 32 + j * 16 + lr;
          out[row * NC + col] = acc[i][j][r];
        }
  }
}

// ---------------- workspace layout ----------------
static constexpr size_t OFF_XB = 0;                        // 4096*768*2
static constexpr size_t OFF_WT = OFF_XB + 6291456;         // 2304*768*2
static constexpr size_t OFF_WTP = OFF_WT + 3538944;        // 768*768*2
static constexpr size_t OFF_Q = OFF_WTP + 1179648;         // 48*1024*64*2
static constexpr size_t OFF_K = OFF_Q + 6291456;
static constexpr size_t OFF_VT = OFF_K + 6291456;
static constexpr size_t OFF_BIAS = OFF_VT + 6291456;       // 12*1024*384*2 bf16
static constexpr size_t OFF_Y = OFF_BIAS + 9437184;        // 4096*768*2
static constexpr size_t OFF_BAR = OFF_Y + 6291456;         // 64 B barrier counters

extern "C" void kernel_launch(void* const* d_in, const int* in_sizes, int n_in,
                              void* d_out, int out_size, void* d_ws, size_t ws_size,
                              hipStream_t stream) {
  const float* x = (const float*)d_in[0];
  const float* Wq = (const float*)d_in[1];
  const float* Wk = (const float*)d_in[2];
  const float* Wv = (const float*)d_in[3];
  const float* Wp = (const float*)d_in[4];
  const float* fw1 = (const float*)d_in[5];
  const float* fb1 = (const float*)d_in[6];
  const float* fw2 = (const float*)d_in[7];
  const float* fb2 = (const float*)d_in[8];
  const float* fc = (const float*)d_in[9];
  const float* fLm = (const float*)d_in[10];

  char* ws = (char*)d_ws;
  u16* xb = (u16*)(ws + OFF_XB);
  u16* Wt = (u16*)(ws + OFF_WT);
  u16* Wtp = (u16*)(ws + OFF_WTP);
  u16* Qb = (u16*)(ws + OFF_Q);
  u16* Kb = (u16*)(ws + OFF_K);
  u16* Vtb = (u16*)(ws + OFF_VT);
  u16* ebiasb = (u16*)(ws + OFF_BIAS);
  u16* Yb = (u16*)(ws + OFF_Y);
  unsigned* bar = (unsigned*)(ws + OFF_BAR);

  hipMemsetAsync(bar, 0, 64, stream);  // zero barrier counters each call (deterministic)
  mega_k<<<NBLK, 256, 0, stream>>>(x, Wq, Wk, Wv, Wp, fw1, fb1, fw2, fb2, fc, fLm,
                                   xb, Wt, Wtp, Qb, Kb, Vtb, ebiasb, Yb,
                                   (float*)d_out, bar);
}

// Round 18
// 68.069 us; speedup vs baseline: 6.5922x; 6.5922x over previous
//
#include <hip/hip_runtime.h>

typedef unsigned short u16;
typedef __attribute__((ext_vector_type(8))) short bf16x8;
typedef __attribute__((ext_vector_type(4))) float f32x4;

#define NB 4
#define NT 1024
#define NC 768
#define NH 12
#define HD 64

__device__ __forceinline__ u16 f2bf(float f) {
  union { float f; unsigned u; } v; v.f = f;
  unsigned r = v.u + 0x7FFFu + ((v.u >> 16) & 1u);
  return (u16)(r >> 16);
}
__device__ __forceinline__ float bf2f(u16 h) {
  union { unsigned u; float f; } v; v.u = ((unsigned)h) << 16;
  return v.f;
}

__device__ __forceinline__ void gld16(const u16* g, u16* l) {
  __builtin_amdgcn_global_load_lds((const __attribute__((address_space(1))) void*)g,
                                   (__attribute__((address_space(3))) void*)l, 16, 0, 0);
}

// ---------------- prep: conv_x (8-wide) | conv_w ----------------
__global__ __launch_bounds__(256) void prep_k(const float* __restrict__ x,
                                              const float* __restrict__ Wq,
                                              const float* __restrict__ Wk,
                                              const float* __restrict__ Wv,
                                              const float* __restrict__ Wp,
                                              u16* __restrict__ xb,
                                              u16* __restrict__ Wt,
                                              u16* __restrict__ Wtp) {
  __shared__ u16 tile[64][65];
  const int bid = blockIdx.x;
  const int tid = threadIdx.x;
  if (bid < 1536) {
    const int base = bid * 2048 + tid * 8;
    const f32x4* xv = (const f32x4*)(x + base);
    f32x4 v0 = xv[0], v1 = xv[1];
    bf16x8 o;
#pragma unroll
    for (int j = 0; j < 4; ++j) {
      o[j] = (short)f2bf(v0[j]);
      o[4 + j] = (short)f2bf(v1[j]);
    }
    *(bf16x8*)(xb + base) = o;
  } else {
    int idx = bid - 1536;
    int z = idx / 144, rem = idx - z * 144;
    int k0 = (rem / 12) * 64, n0 = (rem % 12) * 64;
    const float* src = (z == 0) ? Wq : (z == 1) ? Wk : (z == 2) ? Wv : Wp;
    const int c = tid & 63, r4 = tid >> 6;
#pragma unroll
    for (int p = 0; p < 16; ++p) {
      int kk = p * 4 + r4;
      tile[kk][c] = f2bf(src[(size_t)(k0 + kk) * NC + n0 + c]);
    }
    __syncthreads();
    u16* dst = (z < 3) ? (Wt + (size_t)z * NC * NC) : Wtp;
#pragma unroll
    for (int p = 0; p < 16; ++p) {
      int nn = p * 4 + r4;
      dst[(size_t)(n0 + nn) * NC + k0 + c] = tile[c][nn];
    }
  }
}

// ---------------- fused QKV GEMM + RoPE + head-split | fire table (BK=32, measured best) ----------------
__global__ __launch_bounds__(256, 3) void gemm_qkv_rope(const u16* __restrict__ A,
                                                        const u16* __restrict__ Bt,
                                                        const float* __restrict__ w1,
                                                        const float* __restrict__ b1,
                                                        const float* __restrict__ w2,
                                                        const float* __restrict__ b2,
                                                        const float* __restrict__ cP,
                                                        const float* __restrict__ LmP,
                                                        u16* __restrict__ Qp,
                                                        u16* __restrict__ Kp,
                                                        u16* __restrict__ Vp,
                                                        u16* __restrict__ ebias) {
  constexpr int K = NC;
  __shared__ __align__(16) u16 smem[9472];  // max(As+Bs = 8192, vtx = 4*64*37 = 9472)
  const int bid0 = blockIdx.x;
  const int tid = threadIdx.x;

  if (bid0 >= 576) {  // ---- fire table path ----
    int q = bid0 - 576;
    float c = cP[0], Lm = LmP[0];
    float thresh = fabsf(Lm * 512.0f);
    float pn = fmaxf((float)q, thresh);
    float inv_nl = 1.0f / (logf(fabsf(c * pn) + 1.0f) + 1e-6f);
    for (int idx = tid; idx < 384; idx += 256) {
      int rel = idx - 64;
      float out[NH];
      if (rel >= 0 && rel <= 256) {
        float z = logf(fabsf(c * (float)rel) + 1.0f) * inv_nl;
        float acc[NH];
#pragma unroll
        for (int hh = 0; hh < NH; ++hh) acc[hh] = b2[hh];
#pragma unroll
        for (int j = 0; j < 32; ++j) {
          float hj = fmaxf(z * w1[j] + b1[j], 0.0f);
#pragma unroll
          for (int hh = 0; hh < NH; ++hh) acc[hh] += hj * w2[j * NH + hh];
        }
#pragma unroll
        for (int hh = 0; hh < NH; ++hh) out[hh] = __expf(acc[hh]);
      } else {
#pragma unroll
        for (int hh = 0; hh < NH; ++hh) out[hh] = 0.0f;
      }
#pragma unroll
      for (int hh = 0; hh < NH; ++hh)
        ebias[((size_t)hh * NT + q) * 384 + idx] = f2bf(out[hh]);
    }
    return;
  }

  // ---- GEMM path (128x128, BK=32, XCD-swizzled) ----
  u16* As = smem;
  u16* Bs = smem + 4096;
  const int lin = (bid0 & 7) * 72 + (bid0 >> 3);  // XCD swizzle (576 = 8*72 exact)
  const int m0 = (lin & 31) * 128, n0 = (lin >> 5) * 128;
  const int wid = tid >> 6, lane = tid & 63;
  const int wr = wid >> 1, wc = wid & 1;
  const int lr = lane & 15, lg = lane >> 4, lk = lg << 3;
  const int srow = wid * 16 + (lane >> 2);
  const int scol = (lane & 3) * 8;
  f32x4 acc[4][4] = {};
  const u16* Ag = A + (size_t)(m0 + srow) * K + scol;
  const u16* Bg = Bt + (size_t)(n0 + srow) * K + scol;
  u16* Al = &As[(wid * 16) * 32];
  u16* Bl = &Bs[(wid * 16) * 32];

  for (int k0 = 0; k0 < K; k0 += 32) {
    gld16(Ag + k0, Al);
    gld16(Ag + (size_t)64 * K + k0, Al + 64 * 32);
    gld16(Bg + k0, Bl);
    gld16(Bg + (size_t)64 * K + k0, Bl + 64 * 32);
    __syncthreads();
    bf16x8 af[4], bfv[4];
#pragma unroll
    for (int i = 0; i < 4; ++i)
      af[i] = *(const bf16x8*)&As[(wr * 64 + i * 16 + lr) * 32 + lk];
#pragma unroll
    for (int j = 0; j < 4; ++j)
      bfv[j] = *(const bf16x8*)&Bs[(wc * 64 + j * 16 + lr) * 32 + lk];
#pragma unroll
    for (int i = 0; i < 4; ++i)
#pragma unroll
      for (int j = 0; j < 4; ++j)
        acc[i][j] = __builtin_amdgcn_mfma_f32_16x16x32_bf16(af[i], bfv[j], acc[i][j], 0, 0, 0);
    __syncthreads();  // also fences smem for epilogue reuse (vtx)
  }

  const int rbase = lg * 4;
  const int base_col = n0 + wc * 64;
  const int part = base_col / 768;         // 0=Q 1=K 2=V
  const int h = (base_col % 768) >> 6;
  const int b = m0 >> 10;
  const int bh = b * NH + h;
  const int tbase = (m0 & 1023) + wr * 64;

  if (part < 2) {
    u16* dst = (part == 0 ? Qp : Kp) + ((size_t)bh << 16);
    const float inv0 = __expf(-(float)lr * 0.28782313662425f);          // 10000^(-lr/32)
    const float inv1 = __expf(-(float)(lr + 16) * 0.28782313662425f);
#pragma unroll
    for (int i = 0; i < 4; ++i)
#pragma unroll
      for (int rr = 0; rr < 4; ++rr) {
        const int tl = tbase + i * 16 + rbase + rr;
        float s0, c0, s1, c1;
        __sincosf((float)tl * inv0, &s0, &c0);
        __sincosf((float)tl * inv1, &s1, &c1);
        const float a0 = acc[i][0][rr], a1 = acc[i][1][rr];
        const float a2 = acc[i][2][rr], a3 = acc[i][3][rr];
        const size_t ro = (size_t)tl * HD;
        dst[ro + lr]      = f2bf(a0 * c0 - a2 * s0);
        dst[ro + 16 + lr] = f2bf(a1 * c1 - a3 * s1);
        dst[ro + 32 + lr] = f2bf(a0 * s0 + a2 * c0);
        dst[ro + 48 + lr] = f2bf(a1 * s1 + a3 * c1);
      }
  } else {
    u16* dst = Vp + ((size_t)bh << 16);
    u16* vb = smem + wid * 64 * 37;        // per-wave [64][37] transpose buffer
#pragma unroll
    for (int hf = 0; hf < 2; ++hf) {
#pragma unroll
      for (int i = 0; i < 4; ++i)
#pragma unroll
        for (int rr = 0; rr < 4; ++rr) {
          const int row = i * 16 + rbase + rr;
          vb[row * 37 + lr]      = f2bf(acc[i][2 * hf][rr]);
          vb[row * 37 + 16 + lr] = f2bf(acc[i][2 * hf + 1][rr]);
        }
      asm volatile("s_waitcnt lgkmcnt(0)" ::: "memory");
#pragma unroll
      for (int p = 0; p < 32; ++p) {
        const int d = hf * 32 + p;
        dst[(size_t)d * NT + tbase + lane] = vb[lane * 37 + p];
      }
    }
  }
}

// ---------------- GEMM (m97 BK=32 structure): A[M][K] bf16, Bt[N][K] bf16 ----------------
template <bool F32OUT, int WR, int WC, int AI, int BJ>
__global__ __launch_bounds__(256, 4) void gemm_lds(const u16* __restrict__ A,
                                                   const u16* __restrict__ Bt,
                                                   void* __restrict__ Cv,
                                                   int M, int N, int K) {
  constexpr int BM = WR * AI * 16;
  constexpr int BN = WC * BJ * 16;
  __shared__ u16 As[BM * 32];
  __shared__ u16 Bs[BN * 32];
  const int tid = threadIdx.x;
  const int wid = tid >> 6, lane = tid & 63;
  const int wr = wid / WC, wc = wid % WC;
  const int m0 = blockIdx.x * BM, n0 = blockIdx.y * BN;
  const int lr = lane & 15, lk = (lane >> 4) << 3;
  const int srow = wid * 16 + (lane >> 2);
  const int scol = (lane & 3) * 8;
  f32x4 acc[AI][BJ] = {};
  const u16* Ag = A + (size_t)(m0 + srow) * K + scol;
  const u16* Bg = Bt + (size_t)(n0 + srow) * K + scol;
  u16* Al = &As[(wid * 16) * 32];
  u16* Bl = &Bs[(wid * 16) * 32];

  for (int k0 = 0; k0 < K; k0 += 32) {
#pragma unroll
    for (int ia = 0; ia < BM / 64; ++ia)
      gld16(Ag + (size_t)(ia * 64) * K + k0, Al + ia * 64 * 32);
#pragma unroll
    for (int ib = 0; ib < BN / 64; ++ib)
      gld16(Bg + (size_t)(ib * 64) * K + k0, Bl + ib * 64 * 32);
    __syncthreads();
    bf16x8 af[AI], bfv[BJ];
#pragma unroll
    for (int i = 0; i < AI; ++i)
      af[i] = *(const bf16x8*)&As[(wr * AI * 16 + i * 16 + lr) * 32 + lk];
#pragma unroll
    for (int j = 0; j < BJ; ++j)
      bfv[j] = *(const bf16x8*)&Bs[(wc * BJ * 16 + j * 16 + lr) * 32 + lk];
#pragma unroll
    for (int i = 0; i < AI; ++i)
#pragma unroll
      for (int j = 0; j < BJ; ++j)
        acc[i][j] = __builtin_amdgcn_mfma_f32_16x16x32_bf16(af[i], bfv[j], acc[i][j], 0, 0, 0);
    __syncthreads();
  }
  const int rbase = (lane >> 4) * 4;
#pragma unroll
  for (int i = 0; i < AI; ++i)
#pragma unroll
    for (int j = 0; j < BJ; ++j)
#pragma unroll
      for (int r = 0; r < 4; ++r) {
        size_t row = m0 + wr * AI * 16 + i * 16 + rbase + r;
        size_t col = n0 + wc * BJ * 16 + j * 16 + lr;
        if (F32OUT)
          ((float*)Cv)[row * N + col] = acc[i][j][r];
        else
          ((u16*)Cv)[row * N + col] = f2bf(acc[i][j][r]);
      }
}

// ---------------- windowed attention: LDS-staged K/V, no-max exp, MFMA row-sum ----------------
__global__ __launch_bounds__(256, 3) void attn_k(const u16* __restrict__ Q,
                                                 const u16* __restrict__ K,
                                                 const u16* __restrict__ Vt,
                                                 const u16* __restrict__ ebias,
                                                 u16* __restrict__ Y) {
  __shared__ __align__(16) u16 Ks[2][64][64];
  __shared__ __align__(16) u16 Vs[2][64][64];
  __shared__ __align__(16) u16 plds[4][16][72];
  const int bid = blockIdx.x;
  const int xcd = bid & 7, j = bid >> 3;
  const int qb = j & 15, t6 = j >> 4;
  const int yslot = xcd * 6 + t6;
  const int b = yslot & 3, h = yslot >> 2;
  const int bh = b * NH + h;
  const int Q0 = qb << 6;
  const int tid = threadIdx.x, wid = tid >> 6, lane = tid & 63;
  const int q0 = Q0 + wid * 16;
  const int lr = lane & 15, lg = lane >> 4, lk = lg << 3;
  const u16* Qb = Q + ((size_t)bh << 16);
  const u16* Kb = K + ((size_t)bh << 16);
  const u16* Vb = Vt + ((size_t)bh << 16);
  const u16* ebh = ebias + (size_t)h * NT * 384;

  bf16x8 aq0 = *(const bf16x8*)(Qb + (q0 + lr) * HD + lk);
  bf16x8 aq1 = *(const bf16x8*)(Qb + (q0 + lr) * HD + 32 + lk);
  bf16x8 ones;
#pragma unroll
  for (int i = 0; i < 8; ++i) ones[i] = (short)0x3F80;  // bf16 1.0
  f32x4 yacc[4] = {};
  f32x4 lsum = {};
  u16(*pl)[72] = plds[wid];

  int cstart = Q0 - 256;
  if (cstart < 0) cstart = 0;
  const int n = ((Q0 + 64) - cstart) >> 6;

  const int srow = lane >> 3;
  const int sseg = (lane & 7) ^ srow;
  auto STAGE = [&](int buf, int c) {
#pragma unroll
    for (int i = 0; i < 2; ++i) {
      const int rb = (i * 4 + wid) * 8;
      gld16(Kb + (size_t)(c + rb + srow) * HD + sseg * 8, &Ks[buf][rb][0]);
      gld16(Vb + (size_t)(rb + srow) * NT + c + sseg * 8, &Vs[buf][rb][0]);
    }
  };
  auto LOADEB = [&](float (&e)[4][4], int c) {
#pragma unroll
    for (int kk = 0; kk < 4; ++kk) {
      const int kcol = c + kk * 16 + lr;
#pragma unroll
      for (int r = 0; r < 4; ++r) {
        int qrow = q0 + lg * 4 + r;
        int idx = qrow - kcol + 64;
        idx = idx < 0 ? 0 : (idx > 383 ? 383 : idx);
        e[kk][r] = bf2f(ebh[(size_t)qrow * 384 + idx]);
      }
    }
  };

  STAGE(0, cstart);
  float ebc[4][4];
  LOADEB(ebc, cstart);
  __syncthreads();

  int c = cstart;
  for (int ci = 0; ci < n; ++ci, c += 64) {
    const int cur = ci & 1;
    const bool more = (ci + 1 < n);
    if (more) STAGE(cur ^ 1, c + 64);
    float ebn[4][4];
    if (more) LOADEB(ebn, c + 64);
    const int rsw = (lr & 7) << 4;
#pragma unroll
    for (int kk = 0; kk < 4; ++kk) {
      const char* krow = (const char*)&Ks[cur][kk * 16 + lr][0];
      bf16x8 bk0 = *(const bf16x8*)(krow + ((lg * 16) ^ rsw));
      bf16x8 bk1 = *(const bf16x8*)(krow + ((lg * 16 + 64) ^ rsw));
      f32x4 t = {};
      t = __builtin_amdgcn_mfma_f32_16x16x32_bf16(aq0, bk0, t, 0, 0, 0);
      t = __builtin_amdgcn_mfma_f32_16x16x32_bf16(aq1, bk1, t, 0, 0, 0);
#pragma unroll
      for (int r = 0; r < 4; ++r) {
        float p = __expf(t[r] * 0.125f) * ebc[kk][r];
        pl[lg * 4 + r][kk * 16 + lr] = f2bf(p);
      }
    }
    asm volatile("s_waitcnt lgkmcnt(0)" ::: "memory");
    bf16x8 ap0 = *(const bf16x8*)&pl[lr][lk];
    bf16x8 ap1 = *(const bf16x8*)&pl[lr][32 + lk];
    lsum = __builtin_amdgcn_mfma_f32_16x16x32_bf16(ap0, ones, lsum, 0, 0, 0);
    lsum = __builtin_amdgcn_mfma_f32_16x16x32_bf16(ap1, ones, lsum, 0, 0, 0);
#pragma unroll
    for (int dt = 0; dt < 4; ++dt) {
      const char* vrow = (const char*)&Vs[cur][dt * 16 + lr][0];
      bf16x8 bv0 = *(const bf16x8*)(vrow + ((lg * 16) ^ rsw));
      bf16x8 bv1 = *(const bf16x8*)(vrow + ((lg * 16 + 64) ^ rsw));
      yacc[dt] = __builtin_amdgcn_mfma_f32_16x16x32_bf16(ap0, bv0, yacc[dt], 0, 0, 0);
      yacc[dt] = __builtin_amdgcn_mfma_f32_16x16x32_bf16(ap1, bv1, yacc[dt], 0, 0, 0);
    }
    if (more) {
#pragma unroll
      for (int kk = 0; kk < 4; ++kk)
#pragma unroll
        for (int r = 0; r < 4; ++r) ebc[kk][r] = ebn[kk][r];
    }
    __syncthreads();
  }

  float linv[4];
#pragma unroll
  for (int r = 0; r < 4; ++r) linv[r] = 1.0f / lsum[r];
#pragma unroll
  for (int dt = 0; dt < 4; ++dt)
#pragma unroll
    for (int r = 0; r < 4; ++r) {
      int qrow = q0 + lg * 4 + r;
      int d = dt * 16 + lr;
      Y[(size_t)(b * NT + qrow) * NC + h * HD + d] = f2bf(yacc[dt][r] * linv[r]);
    }
}

// ---------------- workspace layout ----------------
static constexpr size_t OFF_XB = 0;                        // 4096*768*2
static constexpr size_t OFF_WT = OFF_XB + 6291456;         // 2304*768*2
static constexpr size_t OFF_WTP = OFF_WT + 3538944;        // 768*768*2
static constexpr size_t OFF_Q = OFF_WTP + 1179648;         // 48*1024*64*2
static constexpr size_t OFF_K = OFF_Q + 6291456;
static constexpr size_t OFF_VT = OFF_K + 6291456;
static constexpr size_t OFF_BIAS = OFF_VT + 6291456;       // 12*1024*384*2 bf16
static constexpr size_t OFF_Y = OFF_BIAS + 9437184;        // 4096*768*2

extern "C" void kernel_launch(void* const* d_in, const int* in_sizes, int n_in,
                              void* d_out, int out_size, void* d_ws, size_t ws_size,
                              hipStream_t stream) {
  const float* x = (const float*)d_in[0];
  const float* Wq = (const float*)d_in[1];
  const float* Wk = (const float*)d_in[2];
  const float* Wv = (const float*)d_in[3];
  const float* Wp = (const float*)d_in[4];
  const float* fw1 = (const float*)d_in[5];
  const float* fb1 = (const float*)d_in[6];
  const float* fw2 = (const float*)d_in[7];
  const float* fb2 = (const float*)d_in[8];
  const float* fc = (const float*)d_in[9];
  const float* fLm = (const float*)d_in[10];

  char* ws = (char*)d_ws;
  u16* xb = (u16*)(ws + OFF_XB);
  u16* Wt = (u16*)(ws + OFF_WT);
  u16* Wtp = (u16*)(ws + OFF_WTP);
  u16* Qb = (u16*)(ws + OFF_Q);
  u16* Kb = (u16*)(ws + OFF_K);
  u16* Vtb = (u16*)(ws + OFF_VT);
  u16* ebiasb = (u16*)(ws + OFF_BIAS);
  u16* Yb = (u16*)(ws + OFF_Y);

  prep_k<<<2112, 256, 0, stream>>>(x, Wq, Wk, Wv, Wp, xb, Wt, Wtp);
  gemm_qkv_rope<<<1600, 256, 0, stream>>>(xb, Wt, fw1, fb1, fw2, fb2, fc, fLm,
                                          Qb, Kb, Vtb, ebiasb);
  attn_k<<<768, 256, 0, stream>>>(Qb, Kb, Vtb, ebiasb, Yb);
  gemm_lds<true, 2, 2, 4, 2><<<dim3(32, 12), 256, 0, stream>>>(Yb, Wtp, d_out, 4096, 768, 768);
}